// Round 6
// baseline (1313.164 us; speedup 1.0000x reference)
//
#include <hip/hip_runtime.h>
#include <math.h>

#define B_ 128
#define L_ 30
#define M_ 10
#define H_ 256
#define VN_ 32000
#define VCH 10
#define VITER 25     // (VN/VCH)/128

typedef __bf16 bf16;
typedef bf16 bf16x8 __attribute__((ext_vector_type(8)));
typedef float f32x4 __attribute__((ext_vector_type(4)));

#define MFMA(a,b,c) __builtin_amdgcn_mfma_f32_16x16x32_bf16(a, b, c, 0, 0, 0)

__device__ __forceinline__ float rcpf(float x) { return __builtin_amdgcn_rcpf(x); }
__device__ __forceinline__ float sigf(float x) { return rcpf(1.f + __expf(-x)); }
__device__ __forceinline__ float ftanh(float x) {
  float e = __expf(2.f * x);
  return 1.f - 2.f * rcpf(e + 1.f);
}
__device__ __forceinline__ float u2lo(unsigned w) { return __builtin_bit_cast(float, w << 16); }
__device__ __forceinline__ float u2hi(unsigned w) { return __builtin_bit_cast(float, w & 0xffff0000u); }
__device__ __forceinline__ unsigned packbf2(float a, float b) {
  unsigned short lo = __builtin_bit_cast(unsigned short, (bf16)a);
  unsigned short hi = __builtin_bit_cast(unsigned short, (bf16)b);
  return (unsigned)lo | ((unsigned)hi << 16);
}

#if __has_builtin(__builtin_amdgcn_fdot2_f32_bf16)
typedef __bf16 bf16x2 __attribute__((ext_vector_type(2)));
__device__ __forceinline__ float dot2(unsigned x, unsigned w, float c) {
  return __builtin_amdgcn_fdot2_f32_bf16(__builtin_bit_cast(bf16x2, x),
                                         __builtin_bit_cast(bf16x2, w), c, false);
}
#else
__device__ __forceinline__ float dot2(unsigned x, unsigned w, float c) {
  c = fmaf(u2lo(x), u2lo(w), c);
  return fmaf(u2hi(x), u2hi(w), c);
}
#endif

// ---------------------------------------------------------------- weight prep (k-pair packed, n-coalesced)
__global__ __launch_bounds__(256) void k_prep(
    const float* W_ct, const float* W_ih, const float* W_hh,
    const float* W_n, const float* W_k, const float* W_v, const float* W_nv,
    const float* W_hn, const float* W_hk, const float* W_hv,
    const float* W_mk, const float* W_mv, const float* W_g,
    unsigned* WhhP, bf16* Wihb, unsigned* WnkvP, unsigned* WctPH, unsigned* WctP45,
    unsigned* WmP0, unsigned* WmPQ, unsigned* WhdA, unsigned* WhdB, unsigned* WgP,
    bf16* Wnvb) {
  int stride = gridDim.x * blockDim.x;
  int base = blockIdx.x * blockDim.x + threadIdx.x;
  // gates h-part: [k2 128][n 1024]
  for (int i = base; i < 131072; i += stride) {
    int k2 = i >> 10, n = i & 1023;
    WhhP[i] = packbf2(W_hh[n*256 + 2*k2], W_hh[n*256 + 2*k2 + 1]);
  }
  // gates emb-part: plain bf16 row-major [n 1024][k 256] for MFMA k_pregates
  for (int i = base; i < 262144; i += stride) Wihb[i] = (bf16)W_ih[i];
  // hnkv: [k2 128][n 768]
  for (int i = base; i < 98304; i += stride) {
    int k2 = i / 768, n = i - (i/768)*768;
    const float* s = (n < 256) ? W_n : (n < 512) ? W_k : W_v;
    int nn = n & 255;
    WnkvP[i] = packbf2(s[nn*256 + 2*k2], s[nn*256 + 2*k2 + 1]);
  }
  // W_ct cH segs: [X 3][k2 128][n 256]
  for (int i = base; i < 98304; i += stride) {
    int X = i >> 15, r = i & 32767, k2 = r >> 8, n = r & 255;
    int col = X*256 + 2*k2;
    WctPH[i] = packbf2(W_ct[n*1280 + col], W_ct[n*1280 + col + 1]);
  }
  // W_ct cM segs: [X 2][k2 128][n 256]
  for (int i = base; i < 65536; i += stride) {
    int X = i >> 15, r = i & 32767, k2 = r >> 8, n = r & 255;
    int col = 768 + X*256 + 2*k2;
    WctP45[i] = packbf2(W_ct[n*1280 + col], W_ct[n*1280 + col + 1]);
  }
  // mem-attn prev_h seg: [k2 128][c 32]  (c<10: mk, 16<=c<26: mv)
  for (int i = base; i < 4096; i += stride) {
    int k2 = i >> 5, c = i & 31;
    float x0 = 0.f, x1 = 0.f;
    if (c < 10)              { x0 = W_mk[c*1024 + 2*k2]; x1 = W_mk[c*1024 + 2*k2 + 1]; }
    else if (c >= 16 && c < 26) { int m = c-16; x0 = W_mv[m*1024 + 2*k2]; x1 = W_mv[m*1024 + 2*k2 + 1]; }
    WmP0[i] = packbf2(x0, x1);
  }
  // mem-attn cH segs: [X 3][k2 128][c 32]
  for (int i = base; i < 12288; i += stride) {
    int X = i >> 12, r = i & 4095, k2 = r >> 5, c = r & 31;
    int off = 256 + X*256 + 2*k2;
    float x0 = 0.f, x1 = 0.f;
    if (c < 10)              { x0 = W_mk[c*1024 + off]; x1 = W_mk[c*1024 + off + 1]; }
    else if (c >= 16 && c < 26) { int m = c-16; x0 = W_mv[m*1024 + off]; x1 = W_mv[m*1024 + off + 1]; }
    WmPQ[i] = packbf2(x0, x1);
  }
  // attn dA per-step: [d 30][k2 128][c 128]  (c<96: X=c>>5,l=c&31)
  for (int i = base; i < 491520; i += stride) {
    int d = i >> 14, r = i & 16383, k2 = r >> 7, c = r & 127;
    float x0 = 0.f, x1 = 0.f;
    if (c < 96) {
      int X = c >> 5, l = c & 31;
      if (l < 30) {
        const float* W = (X == 0) ? W_hn : (X == 1) ? W_hk : W_hv;
        x0 = W[l*7936 + d*256 + 2*k2]; x1 = W[l*7936 + d*256 + 2*k2 + 1];
      }
    }
    WhdA[i] = packbf2(x0, x1);
  }
  // attn dB (prev_h seg): [k2 128][c 128]
  for (int i = base; i < 16384; i += stride) {
    int k2 = i >> 7, c = i & 127;
    float x0 = 0.f, x1 = 0.f;
    if (c < 96) {
      int X = c >> 5, l = c & 31;
      if (l < 30) {
        const float* W = (X == 0) ? W_hn : (X == 1) ? W_hk : W_hv;
        x0 = W[l*7936 + 2*k2]; x1 = W[l*7936 + 2*k2 + 1];
      }
    }
    WhdB[i] = packbf2(x0, x1);
  }
  for (int i = base; i < 128; i += stride) WgP[i] = packbf2(W_g[2*i], W_g[2*i+1]);
  for (int i = base; i < VN_*H_; i += stride) Wnvb[i] = (bf16)W_nv[i];
}

// ---------------------------------------------------------------- hoisted emb@W_ih via MFMA (29 blocks)
__global__ __launch_bounds__(256) void k_pregates(
    const int* sentence, const float* emb, const bf16* Wihb,
    const float* b_ih, const float* b_hh, float* prehg) {
  extern __shared__ char smp[];
  char* Al = smp;            // 128 x 256 bf16 swz
  char* Bl = smp + 65536;    // 128 x 256 bf16 swz
  __shared__ int tok_s[128];
  int gd = blockIdx.x, t = threadIdx.x, wid = t >> 6, lane = t & 63;
  if (t < 128) tok_s[t] = sentence[t*L_ + gd];
  __syncthreads();
  for (int i = t; i < 128*128; i += 256) {
    int r = i >> 7, k2 = i & 127;
    const float* e = emb + (size_t)tok_s[r]*H_ + 2*k2;
    *(unsigned*)(Al + ((r*512 + k2*4) ^ ((r&7)<<4))) = packbf2(e[0], e[1]);
  }
  __syncthreads();
  bf16x8 afr[8][2];
  #pragma unroll
  for (int kk = 0; kk < 8; ++kk) {
    int kb2 = kk*64 + (lane>>4)*16;
    #pragma unroll
    for (int fi = 0; fi < 2; ++fi) {
      int m = wid*32 + fi*16 + (lane & 15);
      afr[kk][fi] = *(const bf16x8*)(Al + ((m*512 + kb2) ^ ((m&7)<<4)));
    }
  }
  for (int nc = 0; nc < 8; ++nc) {
    int n0 = nc*128;
    for (int i = t; i < 128*32; i += 256) {
      int r = i >> 5, c8 = i & 31;
      int4 v = *(const int4*)(Wihb + (size_t)(n0 + r)*H_ + c8*8);
      *(int4*)(Bl + ((r*512 + c8*16) ^ ((r&7)<<4))) = v;
    }
    __syncthreads();
    f32x4 acc[2][8] = {};
    #pragma unroll
    for (int kk = 0; kk < 8; ++kk) {
      int kb2 = kk*64 + (lane>>4)*16;
      bf16x8 bfr[8];
      #pragma unroll
      for (int fj = 0; fj < 8; ++fj) {
        int n = fj*16 + (lane & 15);
        bfr[fj] = *(const bf16x8*)(Bl + ((n*512 + kb2) ^ ((n&7)<<4)));
      }
      #pragma unroll
      for (int fi = 0; fi < 2; ++fi)
        #pragma unroll
        for (int fj = 0; fj < 8; ++fj)
          acc[fi][fj] = MFMA(afr[kk][fi], bfr[fj], acc[fi][fj]);
    }
    #pragma unroll
    for (int fi = 0; fi < 2; ++fi)
      #pragma unroll
      for (int fj = 0; fj < 8; ++fj)
        #pragma unroll
        for (int r = 0; r < 4; ++r) {
          int row = wid*32 + fi*16 + (lane>>4)*4 + r;
          int col = n0 + fj*16 + (lane & 15);
          prehg[((size_t)gd*128 + row)*1024 + col] = acc[fi][fj][r] + b_ih[col] + b_hh[col];
        }
    __syncthreads();
  }
}

// ---------------------------------------------------------------- recurrence: 128 blocks x 1 batch row, 1024 threads
struct LoopP {
  const int *sentence, *keywords, *categories, *memsz;
  const float *emb;
  const unsigned *WhhP, *WnkvP, *WctPH, *WctP45, *WmP0, *WmPQ, *WhdA, *WhdB, *WgP;
  const float *prehg;
  const float *b_ct, *b_hn, *b_hk, *b_hv, *b_mk, *b_mv, *b_g;
  unsigned* hNb;     // [29*128][128] u32 (bf16 pairs)
  float* gt_all;     // [29*128]
  float* outg;       // [128][30]
};

__global__ __launch_bounds__(1024) void k_loop(LoopP p) {
  extern __shared__ unsigned Su[];
  float* Sf = (float*)Su;
  const int t = threadIdx.x, b = blockIdx.x;
  enum { PH = 0,          // u32 [3][30][128] projections (c0 segs)
         QM = 11520,      // f32 [3][30][32]  mem-attn projections
         P45 = 14400,     // u32 [2][10][128]
         MB = 16960,      // u32 [2][10][128] (init only)
         GA = 19520,      // f32 [1024]
         HP = 20544,      // u32 [128]
         HV = 20672,      // u32 [3][128]
         SW = 21056, ACA = 21152, SWM = 21248, M0 = 21280,
         DA = 21312, DB = 21440,
         BCT = 21568, BH = 21824, BM = 21920, BG = 21952 };

  // ===== init =====
  for (int i = t; i < 2560; i += 1024) {
    int X = i / 1280, r = i - X*1280, m = r >> 7, j = r & 127;
    int ms = p.memsz[b];
    int idx = (X == 0 ? p.keywords : p.categories)[b*M_ + m];
    unsigned u = 0;
    if (m < ms) {
      const float* e = p.emb + (size_t)idx*H_ + 2*j;
      u = packbf2(e[0], e[1]);
    }
    Su[MB + i] = u;
  }
  if (t < 256) Sf[BCT + t] = p.b_ct[t];
  if (t < 96) {
    int X = t >> 5, l = t & 31;
    const float* bh = (X == 0) ? p.b_hn : (X == 1) ? p.b_hk : p.b_hv;
    Sf[BH + t] = (l < 30) ? bh[l] : 0.f;
    Sf[ACA + t] = 0.f;
  }
  if (t < 32) {
    float v = 0.f;
    if (t < 10) v = p.b_mk[t];
    else if (t >= 16 && t < 26) v = p.b_mv[t - 16];
    Sf[BM + t] = v;
  }
  if (t == 0) { Sf[BG] = p.b_g[0]; p.outg[b*L_] = 0.f; }
  __syncthreads();
  if (t < 128) {
    float a0 = 0.f, a1 = 0.f;
    #pragma unroll
    for (int q = 0; q < 20; ++q) {
      unsigned u = Su[MB + q*128 + t];
      a0 += u2lo(u); a1 += u2hi(u);
    }
    float msf = (float)p.memsz[b];
    unsigned up = packbf2(a0 / (2.f * msf), a1 / (2.f * msf));
    Su[HP + t] = up;
    Su[HV + t] = up; Su[HV + 128 + t] = up; Su[HV + 256 + t] = up;
  }
  for (int q = t; q < 2560; q += 1024) {
    int X = q / 1280, r = q - X*1280, m = r >> 7, j = r & 127;
    float a0 = 0.f, a1 = 0.f;
    const uint2* wp = (const uint2*)(p.WctP45 + (X << 15)) + j;
    const unsigned* mb = Su + MB + X*1280 + m*128;
    #pragma unroll 4
    for (int k2 = 0; k2 < 128; ++k2) {
      uint2 w = wp[k2 << 7];
      unsigned u = mb[k2];
      a0 = dot2(u, w.x, a0);
      a1 = dot2(u, w.y, a1);
    }
    Su[P45 + q] = packbf2(a0, a1);
  }
  __syncthreads();

  for (int di = 1; di < L_; ++di) {
    // ---- R1: gates (512 thr, uint2) ∥ dA ∥ dB ∥ M0 ∥ QM ----
    if (t < 512) {
      float2 pre = *(const float2*)&p.prehg[(size_t)(((di-1) << 7) | b)*1024 + 2*t];
      float a0 = 0.f, a1 = 0.f;
      const uint2* wp = (const uint2*)p.WhhP + t;
      #pragma unroll 8
      for (int k2 = 0; k2 < 128; ++k2) {
        uint2 w = wp[k2 << 9];
        unsigned x = Su[HP + k2];
        a0 = dot2(x, w.x, a0);
        a1 = dot2(x, w.y, a1);
      }
      Sf[GA + 2*t] = pre.x + a0;
      Sf[GA + 2*t + 1] = pre.y + a1;
    } else if (t < 640) {     // dA (hist slot di-1 = HV)
      int c = t - 512;
      float a = 0.f;
      const unsigned* wp = p.WhdA + ((size_t)di << 14) + c;
      const unsigned* hv = Su + HV + ((c >> 5) << 7);
      #pragma unroll 8
      for (int k2 = 0; k2 < 128; ++k2) a = dot2(hv[k2], wp[k2 << 7], a);
      Sf[DA + c] = a;
    } else if (t < 768) {     // dB (prev h)
      int c = t - 640;
      float a = 0.f;
      const unsigned* wp = p.WhdB + c;
      #pragma unroll 8
      for (int k2 = 0; k2 < 128; ++k2) a = dot2(Su[HP + k2], wp[k2 << 7], a);
      Sf[DB + c] = a;
    } else if (t < 800) {     // M0 (prev_h part of mem-attn)
      int c = t - 768;
      float a = 0.f;
      const unsigned* wp = p.WmP0 + c;
      #pragma unroll 8
      for (int k2 = 0; k2 < 128; ++k2) a = dot2(Su[HP + k2], wp[k2 << 5], a);
      Sf[M0 + c] = a;
    } else if (t < 896) {     // QM append for slot di-1
      int q = t - 800, X = q >> 5, c = q & 31;
      float a = 0.f;
      const unsigned* wp = p.WmPQ + (X << 12) + c;
      const unsigned* hv = Su + HV + (X << 7);
      #pragma unroll 8
      for (int k2 = 0; k2 < 128; ++k2) a = dot2(hv[k2], wp[k2 << 5], a);
      Sf[QM + (X*30 + di-1)*32 + c] = a;
    }
    __syncthreads();
    // ---- R2: sw (96) ∥ PH append (384) ----
    if (t < 96) {
      float a = Sf[ACA + t] + Sf[DA + t];
      Sf[ACA + t] = a;
      Sf[SW + t] = ftanh(a + Sf[DB + t] + Sf[BH + t]);
    } else if (t >= 128 && t < 512) {
      int q = t - 128, X = q >> 7, j = q & 127;
      float a0 = 0.f, a1 = 0.f;
      const unsigned* hv = Su + HV + (X << 7);
      const uint2* wp = (const uint2*)(p.WctPH + (X << 15)) + j;
      #pragma unroll 4
      for (int k2 = 0; k2 < 128; ++k2) {
        uint2 w = wp[k2 << 7];
        a0 = dot2(hv[k2], w.x, a0);
        a1 = dot2(hv[k2], w.y, a1);
      }
      Su[PH + (X*30 + di-1)*128 + j] = packbf2(a0, a1);
    }
    __syncthreads();
    // ---- R3: swm (3 parallel accum chains) ----
    if (t < 32) {
      bool valid = (t < 10) || (t >= 16 && t < 26);
      if (valid) {
        float aN = 0.f, aK = 0.f, aV = 0.f;
        const float* sw0 = Sf + SW;
        const float* q0 = Sf + QM + t;
        for (int l = 0; l < di; ++l) {
          aN = fmaf(sw0[l],      q0[l*32],        aN);
          aK = fmaf(sw0[32 + l], q0[960 + l*32],  aK);
          aV = fmaf(sw0[64 + l], q0[1920 + l*32], aV);
        }
        Sf[SWM + t] = ftanh(Sf[M0 + t] + Sf[BM + t] + aN + aK + aV);
      }
    }
    __syncthreads();
    // ---- R4: c0 + LSTM cell (pairs, split accum chains) ----
    if (t < 128) {
      float a0 = Sf[BCT + 2*t], a1 = Sf[BCT + 2*t + 1];
      for (int X = 0; X < 3; ++X) {
        const float* swp = Sf + SW + X*32;
        const unsigned* php = Su + PH + X*3840 + t;
        float e0 = 0.f, e1 = 0.f, o0 = 0.f, o1 = 0.f;
        int l = 0;
        for (; l + 1 < di; l += 2) {
          float s0 = swp[l], s1 = swp[l+1];
          unsigned ua = php[l*128], ub = php[(l+1)*128];
          e0 = fmaf(s0, u2lo(ua), e0); e1 = fmaf(s0, u2hi(ua), e1);
          o0 = fmaf(s1, u2lo(ub), o0); o1 = fmaf(s1, u2hi(ub), o1);
        }
        if (l < di) {
          float s = swp[l]; unsigned u = php[l*128];
          e0 = fmaf(s, u2lo(u), e0); e1 = fmaf(s, u2hi(u), e1);
        }
        a0 += e0 + o0; a1 += e1 + o1;
      }
      {
        float p0 = 0.f, p1 = 0.f, q0 = 0.f, q1 = 0.f;
        #pragma unroll
        for (int m = 0; m < 10; ++m) {
          float sk = Sf[SWM + m], sv = Sf[SWM + 16 + m];
          unsigned uk = Su[P45 + m*128 + t], uv = Su[P45 + 1280 + m*128 + t];
          p0 = fmaf(sk, u2lo(uk), p0); p1 = fmaf(sk, u2hi(uk), p1);
          q0 = fmaf(sv, u2lo(uv), q0); q1 = fmaf(sv, u2hi(uv), q1);
        }
        a0 += p0 + q0; a1 += p1 + q1;
      }
      int n0 = 2*t;
      float gi0 = Sf[GA+n0],   gf0 = Sf[GA+256+n0], gg0 = Sf[GA+512+n0], go0 = Sf[GA+768+n0];
      float gi1 = Sf[GA+n0+1], gf1 = Sf[GA+257+n0], gg1 = Sf[GA+513+n0], go1 = Sf[GA+769+n0];
      float cc0 = sigf(gf0)*a0 + sigf(gi0)*ftanh(gg0);
      float cc1 = sigf(gf1)*a1 + sigf(gi1)*ftanh(gg1);
      float h0 = sigf(go0)*ftanh(cc0);
      float h1 = sigf(go1)*ftanh(cc1);
      Su[HP + t] = packbf2(h0, h1);
    }
    __syncthreads();
    // ---- R5: hN/hK/hV + gt ----
    if (t < 384) {
      int X = t >> 7, j = t & 127;
      float a0 = 0.f, a1 = 0.f;
      const uint2* wp = (const uint2*)p.WnkvP + t;
      #pragma unroll 4
      for (int k2 = 0; k2 < 128; ++k2) {
        uint2 w = wp[k2*384];
        unsigned u = Su[HP + k2];
        a0 = dot2(u, w.x, a0);
        a1 = dot2(u, w.y, a1);
      }
      unsigned up = packbf2(a0, a1);
      Su[HV + t] = up;
      if (X == 0) p.hNb[(size_t)(((di-1) << 7) | b)*128 + j] = up;
    } else if (t >= 448 && t < 512) {
      int j = t - 448;
      float a = dot2(Su[HP + 2*j], p.WgP[2*j], 0.f);
      a = dot2(Su[HP + 2*j + 1], p.WgP[2*j + 1], a);
      #pragma unroll
      for (int o = 1; o < 64; o <<= 1) a += __shfl_xor(a, o);
      if (j == 0) {
        float g = sigf(a + Sf[BG]);
        p.gt_all[((di-1) << 7) | b] = g;
        p.outg[b*L_ + di] = g;
      }
    }
    __syncthreads();
  }
}

// ---------------------------------------------------------------- batched vocab GEMM + streaming LSE (reg-dbuf B)
__global__ __launch_bounds__(256) void k_vocab(
    const bf16* hNb, const bf16* Wnvb, const float* b_nv, float2* pmps) {
  extern __shared__ char smv[];
  char* Al = smv;             // 128 x 256 bf16, swizzled
  char* Bl = smv + 65536;     // 128 x 256 bf16, swizzled
  int blk = blockIdx.x;
  int tile = blk / VCH, ch = blk - tile*VCH;
  int t = threadIdx.x, wid = t >> 6, lane = t & 63;
  for (int i = t; i < 128*32; i += 256) {
    int r = i >> 5, c8 = i & 31;
    int4 v = *(const int4*)(hNb + ((size_t)tile*128 + r)*H_ + c8*8);
    *(int4*)(Al + ((r*512 + c8*16) ^ ((r&7)<<4))) = v;
  }
  int v0 = ch * (VN_/VCH);
  // preload chunk 0 into regs
  int4 rg[16];
  #pragma unroll
  for (int q = 0; q < 16; ++q) {
    int i = t + q*256;
    int r = i >> 5, c8 = i & 31;
    rg[q] = *(const int4*)(Wnvb + (size_t)(v0 + r)*H_ + c8*8);
  }
  __syncthreads();
  bf16x8 afr[8][2];
  #pragma unroll
  for (int kk = 0; kk < 8; ++kk) {
    int kb2 = kk*64 + (lane>>4)*16;
    #pragma unroll
    for (int fi = 0; fi < 2; ++fi) {
      int m = wid*32 + fi*16 + (lane & 15);
      afr[kk][fi] = *(const bf16x8*)(Al + ((m*512 + kb2) ^ ((m&7)<<4)));
    }
  }
  float Mrun[2][4], Srun[2][4];
  #pragma unroll
  for (int fi = 0; fi < 2; ++fi)
    #pragma unroll
    for (int r = 0; r < 4; ++r) { Mrun[fi][r] = -1e30f; Srun[fi][r] = 0.f; }
  for (int it = 0; it < VITER; ++it) {
    // write staged regs -> LDS
    #pragma unroll
    for (int q = 0; q < 16; ++q) {
      int i = t + q*256;
      int r = i >> 5, c8 = i & 31;
      *(int4*)(Bl + ((r*512 + c8*16) ^ ((r&7)<<4))) = rg[q];
    }
    __syncthreads();
    // issue next chunk's loads (overlap with MFMA below)
    if (it + 1 < VITER) {
      #pragma unroll
      for (int q = 0; q < 16; ++q) {
        int i = t + q*256;
        int r = i >> 5, c8 = i & 31;
        rg[q] = *(const int4*)(Wnvb + (size_t)(v0 + (it+1)*128 + r)*H_ + c8*8);
      }
    }
    f32x4 acc[2][8] = {};
    #pragma unroll
    for (int kk = 0; kk < 8; ++kk) {
      int kb2 = kk*64 + (lane>>4)*16;
      bf16x8 bfr[8];
      #pragma unroll
      for (int fj = 0; fj < 8; ++fj) {
        int n = fj*16 + (lane & 15);
        bfr[fj] = *(const bf16x8*)(Bl + ((n*512 + kb2) ^ ((n&7)<<4)));
      }
      #pragma unroll
      for (int fi = 0; fi < 2; ++fi)
        #pragma unroll
        for (int fj = 0; fj < 8; ++fj)
          acc[fi][fj] = MFMA(afr[kk][fi], bfr[fj], acc[fi][fj]);
    }
    float bb[8];
    #pragma unroll
    for (int fj = 0; fj < 8; ++fj) bb[fj] = b_nv[v0 + it*128 + fj*16 + (lane & 15)];
    #pragma unroll
    for (int fi = 0; fi < 2; ++fi)
      #pragma unroll
      for (int r = 0; r < 4; ++r) {
        float mi = acc[fi][0][r] + bb[0];
        #pragma unroll
        for (int fj = 1; fj < 8; ++fj) mi = fmaxf(mi, acc[fi][fj][r] + bb[fj]);
        for (int o = 1; o < 16; o <<= 1) mi = fmaxf(mi, __shfl_xor(mi, o));
        float si = 0.f;
        #pragma unroll
        for (int fj = 0; fj < 8; ++fj) si += __expf(acc[fi][fj][r] + bb[fj] - mi);
        for (int o = 1; o < 16; o <<= 1) si += __shfl_xor(si, o);
        float M2 = fmaxf(Mrun[fi][r], mi);
        Srun[fi][r] = Srun[fi][r]*__expf(Mrun[fi][r] - M2) + si*__expf(mi - M2);
        Mrun[fi][r] = M2;
      }
    __syncthreads();
  }
  #pragma unroll
  for (int fi = 0; fi < 2; ++fi)
    #pragma unroll
    for (int r = 0; r < 4; ++r)
      if ((lane & 15) == 0) {
        int row = wid*32 + fi*16 + (lane>>4)*4 + r;
        int g = tile*128 + row;
        pmps[(size_t)g*VCH + ch] = make_float2(Mrun[fi][r], Srun[fi][r]);
      }
}

// ---------------------------------------------------------------- per-step loss combine
__global__ __launch_bounds__(128) void k_combine(
    const float2* pmps, const unsigned* hNb, const float* W_nv, const float* b_nv,
    const float* gt_all, const int* sentence, float* loss_part) {
  __shared__ float red[128];
  int tile = blockIdx.x, bb = threadIdx.x;
  int g = tile*128 + bb;
  float M = -1e30f, Ssum = 0.f;
  #pragma unroll
  for (int c = 0; c < VCH; ++c) {
    float2 v = pmps[(size_t)g*VCH + c];
    float M2 = fmaxf(M, v.x);
    Ssum = Ssum*__expf(M - M2) + v.y*__expf(v.x - M2);
    M = M2;
  }
  int tok = sentence[bb*L_ + tile + 1];
  float z = b_nv[tok];
  const unsigned* hu = hNb + (size_t)g*128;
  const float* wr = W_nv + (size_t)tok*H_;
  #pragma unroll 8
  for (int k = 0; k < 128; ++k) {
    unsigned w2 = hu[k];
    z += u2lo(w2)*wr[2*k] + u2hi(w2)*wr[2*k + 1];
  }
  float term = -(z - M - __logf(Ssum) + __logf(gt_all[g]));
  red[bb] = term;
  __syncthreads();
  for (int o = 64; o > 0; o >>= 1) {
    if (bb < o) red[bb] += red[bb + o];
    __syncthreads();
  }
  if (bb == 0) loss_part[tile] = red[0];
}

__global__ __launch_bounds__(64) void k_fin(const float* lp, float* out) {
  int t = threadIdx.x;
  float v = (t < 29) ? lp[t] : 0.f;
  for (int o = 1; o < 64; o <<= 1) v += __shfl_xor(v, o);
  if (t == 0) out[0] = v;
}

// ---------------------------------------------------------------- launch
extern "C" void kernel_launch(void* const* d_in, const int* in_sizes, int n_in,
                              void* d_out, int out_size, void* d_ws, size_t ws_size,
                              hipStream_t stream) {
  const int* sentence  = (const int*)d_in[0];
  const int* keywords  = (const int*)d_in[1];
  const int* categories= (const int*)d_in[2];
  const int* memsz     = (const int*)d_in[3];
  const float* emb  = (const float*)d_in[5];
  const float* W_ct = (const float*)d_in[6];
  const float* b_ct = (const float*)d_in[7];
  const float* W_ih = (const float*)d_in[8];
  const float* W_hh = (const float*)d_in[9];
  const float* b_ih = (const float*)d_in[10];
  const float* b_hh = (const float*)d_in[11];
  const float* W_n  = (const float*)d_in[12];
  const float* W_k  = (const float*)d_in[13];
  const float* W_v  = (const float*)d_in[14];
  const float* W_nv = (const float*)d_in[15];
  const float* b_nv = (const float*)d_in[16];
  const float* W_g  = (const float*)d_in[17];
  const float* b_g  = (const float*)d_in[18];
  const float* W_hn = (const float*)d_in[19];
  const float* b_hn = (const float*)d_in[20];
  const float* W_hk = (const float*)d_in[21];
  const float* b_hk = (const float*)d_in[22];
  const float* W_hv = (const float*)d_in[23];
  const float* b_hv = (const float*)d_in[24];
  const float* W_mk = (const float*)d_in[25];
  const float* b_mk = (const float*)d_in[26];
  const float* W_mv = (const float*)d_in[27];
  const float* b_mv = (const float*)d_in[28];
  float* out = (float*)d_out;

  char* wsp = (char*)d_ws;
  size_t off = 0;
  auto alloc = [&](size_t bytes) -> void* {
    void* pp = wsp + off;
    off = (off + bytes + 255) & ~(size_t)255;
    return pp;
  };
  unsigned* WhhP   = (unsigned*)alloc((size_t)131072*4);
  bf16* Wihb       = (bf16*)alloc((size_t)262144*2);
  unsigned* WnkvP  = (unsigned*)alloc((size_t)98304*4);
  unsigned* WctPH  = (unsigned*)alloc((size_t)98304*4);
  unsigned* WctP45 = (unsigned*)alloc((size_t)65536*4);
  unsigned* WmP0   = (unsigned*)alloc((size_t)4096*4);
  unsigned* WmPQ   = (unsigned*)alloc((size_t)12288*4);
  unsigned* WhdA   = (unsigned*)alloc((size_t)491520*4);
  unsigned* WhdB   = (unsigned*)alloc((size_t)16384*4);
  unsigned* WgP    = (unsigned*)alloc((size_t)128*4);
  bf16* Wnvb       = (bf16*)alloc((size_t)VN_*H_*2);
  float* prehg     = (float*)alloc((size_t)29*B_*1024*4);
  unsigned* hNb    = (unsigned*)alloc((size_t)29*B_*128*4);
  float* gt_all    = (float*)alloc((size_t)29*B_*4);
  float2* pmps     = (float2*)alloc((size_t)29*B_*VCH*8);
  float* loss_part = (float*)alloc(29*4);

  k_prep<<<1024, 256, 0, stream>>>(W_ct, W_ih, W_hh, W_n, W_k, W_v, W_nv,
      W_hn, W_hk, W_hv, W_mk, W_mv, W_g,
      WhhP, Wihb, WnkvP, WctPH, WctP45, WmP0, WmPQ, WhdA, WhdB, WgP, Wnvb);
  k_pregates<<<29, 256, 131072, stream>>>(sentence, emb, Wihb, b_ih, b_hh, prehg);

  LoopP P;
  P.sentence = sentence; P.keywords = keywords; P.categories = categories; P.memsz = memsz;
  P.emb = emb;
  P.WhhP = WhhP; P.WnkvP = WnkvP; P.WctPH = WctPH; P.WctP45 = WctP45;
  P.WmP0 = WmP0; P.WmPQ = WmPQ; P.WhdA = WhdA; P.WhdB = WhdB; P.WgP = WgP;
  P.prehg = prehg;
  P.b_ct = b_ct; P.b_hn = b_hn; P.b_hk = b_hk; P.b_hv = b_hv;
  P.b_mk = b_mk; P.b_mv = b_mv; P.b_g = b_g;
  P.hNb = hNb; P.gt_all = gt_all; P.outg = out + 1;

  k_loop<<<B_, 1024, 87812, stream>>>(P);
  k_vocab<<<29*VCH, 256, 131072, stream>>>((const bf16*)hNb, Wnvb, b_nv, pmps);
  k_combine<<<29, 128, 0, stream>>>(pmps, hNb, W_nv, b_nv, gt_all, sentence, loss_part);
  k_fin<<<1, 64, 0, stream>>>(loss_part, out);
}

// Round 7
// 1062.845 us; speedup vs baseline: 1.2355x; 1.2355x over previous
//
#include <hip/hip_runtime.h>
#include <math.h>

#define B_ 128
#define L_ 30
#define M_ 10
#define H_ 256
#define VN_ 32000
#define NCHK 250     // vocab chunks of 128 cols
#define NG 3712      // 29*128 rows

typedef __bf16 bf16;
typedef bf16 bf16x8 __attribute__((ext_vector_type(8)));
typedef float f32x4 __attribute__((ext_vector_type(4)));

#define MFMA(a,b,c) __builtin_amdgcn_mfma_f32_16x16x32_bf16(a, b, c, 0, 0, 0)

__device__ __forceinline__ float rcpf(float x) { return __builtin_amdgcn_rcpf(x); }
__device__ __forceinline__ float sigf(float x) { return rcpf(1.f + __expf(-x)); }
__device__ __forceinline__ float ftanh(float x) {
  float e = __expf(2.f * x);
  return 1.f - 2.f * rcpf(e + 1.f);
}
__device__ __forceinline__ float u2lo(unsigned w) { return __builtin_bit_cast(float, w << 16); }
__device__ __forceinline__ float u2hi(unsigned w) { return __builtin_bit_cast(float, w & 0xffff0000u); }
__device__ __forceinline__ unsigned packbf2(float a, float b) {
  unsigned short lo = __builtin_bit_cast(unsigned short, (bf16)a);
  unsigned short hi = __builtin_bit_cast(unsigned short, (bf16)b);
  return (unsigned)lo | ((unsigned)hi << 16);
}

#if __has_builtin(__builtin_amdgcn_fdot2_f32_bf16)
typedef __bf16 bf16x2 __attribute__((ext_vector_type(2)));
__device__ __forceinline__ float dot2(unsigned x, unsigned w, float c) {
  return __builtin_amdgcn_fdot2_f32_bf16(__builtin_bit_cast(bf16x2, x),
                                         __builtin_bit_cast(bf16x2, w), c, false);
}
#else
__device__ __forceinline__ float dot2(unsigned x, unsigned w, float c) {
  c = fmaf(u2lo(x), u2lo(w), c);
  return fmaf(u2hi(x), u2hi(w), c);
}
#endif

// ---------------------------------------------------------------- weight prep (k-pair packed, n-coalesced)
__global__ __launch_bounds__(256) void k_prep(
    const float* W_ct, const float* W_ih, const float* W_hh,
    const float* W_n, const float* W_k, const float* W_v, const float* W_nv,
    const float* W_hn, const float* W_hk, const float* W_hv,
    const float* W_mk, const float* W_mv, const float* W_g,
    unsigned* WhhP, bf16* Wihb, unsigned* WnkvP, unsigned* WctPH, unsigned* WctP45,
    unsigned* WmP0, unsigned* WmPQ, unsigned* WhdA, unsigned* WhdB, unsigned* WgP,
    bf16* Wnvb) {
  int stride = gridDim.x * blockDim.x;
  int base = blockIdx.x * blockDim.x + threadIdx.x;
  // gates h-part: [k2 128][n 1024]
  for (int i = base; i < 131072; i += stride) {
    int k2 = i >> 10, n = i & 1023;
    WhhP[i] = packbf2(W_hh[n*256 + 2*k2], W_hh[n*256 + 2*k2 + 1]);
  }
  // gates emb-part: plain bf16 row-major [n 1024][k 256] for MFMA k_pregates
  for (int i = base; i < 262144; i += stride) Wihb[i] = (bf16)W_ih[i];
  // hnkv: [k2 128][n 768]
  for (int i = base; i < 98304; i += stride) {
    int k2 = i / 768, n = i - (i/768)*768;
    const float* s = (n < 256) ? W_n : (n < 512) ? W_k : W_v;
    int nn = n & 255;
    WnkvP[i] = packbf2(s[nn*256 + 2*k2], s[nn*256 + 2*k2 + 1]);
  }
  // W_ct cH segs: [X 3][k2 128][n 256]
  for (int i = base; i < 98304; i += stride) {
    int X = i >> 15, r = i & 32767, k2 = r >> 8, n = r & 255;
    int col = X*256 + 2*k2;
    WctPH[i] = packbf2(W_ct[n*1280 + col], W_ct[n*1280 + col + 1]);
  }
  // W_ct cM segs: [X 2][k2 128][n 256]
  for (int i = base; i < 65536; i += stride) {
    int X = i >> 15, r = i & 32767, k2 = r >> 8, n = r & 255;
    int col = 768 + X*256 + 2*k2;
    WctP45[i] = packbf2(W_ct[n*1280 + col], W_ct[n*1280 + col + 1]);
  }
  // mem-attn prev_h seg: [k2 128][c 32]  (c<10: mk, 16<=c<26: mv)
  for (int i = base; i < 4096; i += stride) {
    int k2 = i >> 5, c = i & 31;
    float x0 = 0.f, x1 = 0.f;
    if (c < 10)              { x0 = W_mk[c*1024 + 2*k2]; x1 = W_mk[c*1024 + 2*k2 + 1]; }
    else if (c >= 16 && c < 26) { int m = c-16; x0 = W_mv[m*1024 + 2*k2]; x1 = W_mv[m*1024 + 2*k2 + 1]; }
    WmP0[i] = packbf2(x0, x1);
  }
  // mem-attn cH segs: [X 3][k2 128][c 32]
  for (int i = base; i < 12288; i += stride) {
    int X = i >> 12, r = i & 4095, k2 = r >> 5, c = r & 31;
    int off = 256 + X*256 + 2*k2;
    float x0 = 0.f, x1 = 0.f;
    if (c < 10)              { x0 = W_mk[c*1024 + off]; x1 = W_mk[c*1024 + off + 1]; }
    else if (c >= 16 && c < 26) { int m = c-16; x0 = W_mv[m*1024 + off]; x1 = W_mv[m*1024 + off + 1]; }
    WmPQ[i] = packbf2(x0, x1);
  }
  // attn dA per-step: [d 30][k2 128][c 128]  (c<96: X=c>>5,l=c&31)
  for (int i = base; i < 491520; i += stride) {
    int d = i >> 14, r = i & 16383, k2 = r >> 7, c = r & 127;
    float x0 = 0.f, x1 = 0.f;
    if (c < 96) {
      int X = c >> 5, l = c & 31;
      if (l < 30) {
        const float* W = (X == 0) ? W_hn : (X == 1) ? W_hk : W_hv;
        x0 = W[l*7936 + d*256 + 2*k2]; x1 = W[l*7936 + d*256 + 2*k2 + 1];
      }
    }
    WhdA[i] = packbf2(x0, x1);
  }
  // attn dB (prev_h seg): [k2 128][c 128]
  for (int i = base; i < 16384; i += stride) {
    int k2 = i >> 7, c = i & 127;
    float x0 = 0.f, x1 = 0.f;
    if (c < 96) {
      int X = c >> 5, l = c & 31;
      if (l < 30) {
        const float* W = (X == 0) ? W_hn : (X == 1) ? W_hk : W_hv;
        x0 = W[l*7936 + 2*k2]; x1 = W[l*7936 + 2*k2 + 1];
      }
    }
    WhdB[i] = packbf2(x0, x1);
  }
  for (int i = base; i < 128; i += stride) WgP[i] = packbf2(W_g[2*i], W_g[2*i+1]);
  for (int i = base; i < VN_*H_; i += stride) Wnvb[i] = (bf16)W_nv[i];
}

// ---------------------------------------------------------------- hoisted emb@W_ih via MFMA (29 blocks)
__global__ __launch_bounds__(256) void k_pregates(
    const int* sentence, const float* emb, const bf16* Wihb,
    const float* b_ih, const float* b_hh, float* prehg) {
  extern __shared__ char smp[];
  char* Al = smp;            // 128 x 256 bf16 swz
  char* Bl = smp + 65536;    // 128 x 256 bf16 swz
  __shared__ int tok_s[128];
  int gd = blockIdx.x, t = threadIdx.x, wid = t >> 6, lane = t & 63;
  if (t < 128) tok_s[t] = sentence[t*L_ + gd];
  __syncthreads();
  for (int i = t; i < 128*128; i += 256) {
    int r = i >> 7, k2 = i & 127;
    const float* e = emb + (size_t)tok_s[r]*H_ + 2*k2;
    *(unsigned*)(Al + ((r*512 + k2*4) ^ ((r&7)<<4))) = packbf2(e[0], e[1]);
  }
  __syncthreads();
  bf16x8 afr[8][2];
  #pragma unroll
  for (int kk = 0; kk < 8; ++kk) {
    int kb2 = kk*64 + (lane>>4)*16;
    #pragma unroll
    for (int fi = 0; fi < 2; ++fi) {
      int m = wid*32 + fi*16 + (lane & 15);
      afr[kk][fi] = *(const bf16x8*)(Al + ((m*512 + kb2) ^ ((m&7)<<4)));
    }
  }
  for (int nc = 0; nc < 8; ++nc) {
    int n0 = nc*128;
    for (int i = t; i < 128*32; i += 256) {
      int r = i >> 5, c8 = i & 31;
      int4 v = *(const int4*)(Wihb + (size_t)(n0 + r)*H_ + c8*8);
      *(int4*)(Bl + ((r*512 + c8*16) ^ ((r&7)<<4))) = v;
    }
    __syncthreads();
    f32x4 acc[2][8] = {};
    #pragma unroll
    for (int kk = 0; kk < 8; ++kk) {
      int kb2 = kk*64 + (lane>>4)*16;
      bf16x8 bfr[8];
      #pragma unroll
      for (int fj = 0; fj < 8; ++fj) {
        int n = fj*16 + (lane & 15);
        bfr[fj] = *(const bf16x8*)(Bl + ((n*512 + kb2) ^ ((n&7)<<4)));
      }
      #pragma unroll
      for (int fi = 0; fi < 2; ++fi)
        #pragma unroll
        for (int fj = 0; fj < 8; ++fj)
          acc[fi][fj] = MFMA(afr[kk][fi], bfr[fj], acc[fi][fj]);
    }
    #pragma unroll
    for (int fi = 0; fi < 2; ++fi)
      #pragma unroll
      for (int fj = 0; fj < 8; ++fj)
        #pragma unroll
        for (int r = 0; r < 4; ++r) {
          int row = wid*32 + fi*16 + (lane>>4)*4 + r;
          int col = n0 + fj*16 + (lane & 15);
          prehg[((size_t)gd*128 + row)*1024 + col] = acc[fi][fj][r] + b_ih[col] + b_hh[col];
        }
    __syncthreads();
  }
}

// ---------------------------------------------------------------- recurrence: 128 blocks x 1 batch row, 1024 threads
// (round-5 structure verbatim — known-good 650 us)
struct LoopP {
  const int *sentence, *keywords, *categories, *memsz;
  const float *emb;
  const unsigned *WhhP, *WnkvP, *WctPH, *WctP45, *WmP0, *WmPQ, *WhdA, *WhdB, *WgP;
  const float *prehg;
  const float *b_ct, *b_hn, *b_hk, *b_hv, *b_mk, *b_mv, *b_g;
  unsigned* hNb;     // [29*128][128] u32 (bf16 pairs)
  float* gt_all;     // [29*128]
  float* outg;       // [128][30]
};

__global__ __launch_bounds__(1024) void k_loop(LoopP p) {
  extern __shared__ unsigned Su[];
  float* Sf = (float*)Su;
  const int t = threadIdx.x, b = blockIdx.x;
  enum { PH = 0,          // u32 [3][30][128] projections (c0 segs)
         QM = 11520,      // f32 [3][30][32]  mem-attn projections
         P45 = 14400,     // u32 [2][10][128]
         MB = 16960,      // u32 [2][10][128] (init only)
         GA = 19520,      // f32 [1024]
         HP = 20544,      // u32 [128]
         HV = 20672,      // u32 [3][128]
         SW = 21056, ACA = 21152, SWM = 21248, M0 = 21280,
         DA = 21312, DB = 21440,
         BCT = 21568, BH = 21824, BM = 21920, BG = 21952 };

  // ===== init =====
  for (int i = t; i < 2560; i += 1024) {
    int X = i / 1280, r = i - X*1280, m = r >> 7, j = r & 127;
    int ms = p.memsz[b];
    int idx = (X == 0 ? p.keywords : p.categories)[b*M_ + m];
    unsigned u = 0;
    if (m < ms) {
      const float* e = p.emb + (size_t)idx*H_ + 2*j;
      u = packbf2(e[0], e[1]);
    }
    Su[MB + i] = u;
  }
  if (t < 256) Sf[BCT + t] = p.b_ct[t];
  if (t < 96) {
    int X = t >> 5, l = t & 31;
    const float* bh = (X == 0) ? p.b_hn : (X == 1) ? p.b_hk : p.b_hv;
    Sf[BH + t] = (l < 30) ? bh[l] : 0.f;
    Sf[ACA + t] = 0.f;
  }
  if (t < 32) {
    float v = 0.f;
    if (t < 10) v = p.b_mk[t];
    else if (t >= 16 && t < 26) v = p.b_mv[t - 16];
    Sf[BM + t] = v;
  }
  if (t == 0) { Sf[BG] = p.b_g[0]; p.outg[b*L_] = 0.f; }
  __syncthreads();
  if (t < 128) {
    float a0 = 0.f, a1 = 0.f;
    #pragma unroll
    for (int q = 0; q < 20; ++q) {
      unsigned u = Su[MB + q*128 + t];
      a0 += u2lo(u); a1 += u2hi(u);
    }
    float msf = (float)p.memsz[b];
    unsigned up = packbf2(a0 / (2.f * msf), a1 / (2.f * msf));
    Su[HP + t] = up;
    Su[HV + t] = up; Su[HV + 128 + t] = up; Su[HV + 256 + t] = up;
  }
  for (int q = t; q < 2560; q += 1024) {
    int X = q / 1280, r = q - X*1280, m = r >> 7, j = r & 127;
    float a0 = 0.f, a1 = 0.f;
    const uint2* wp = (const uint2*)(p.WctP45 + (X << 15)) + j;
    const unsigned* mb = Su + MB + X*1280 + m*128;
    #pragma unroll 4
    for (int k2 = 0; k2 < 128; ++k2) {
      uint2 w = wp[k2 << 7];
      unsigned u = mb[k2];
      a0 = dot2(u, w.x, a0);
      a1 = dot2(u, w.y, a1);
    }
    Su[P45 + q] = packbf2(a0, a1);
  }
  __syncthreads();

  for (int di = 1; di < L_; ++di) {
    // ---- R1: gates (all threads) + slot projections + logits ----
    {
      const float pre = p.prehg[(size_t)(((di-1) << 7) | b)*1024 + t];
      float e0 = 0.f, e1 = 0.f;
      const unsigned* wp = p.WhhP + t;
      #pragma unroll 8
      for (int k2 = 0; k2 < 128; k2 += 2) {
        e0 = dot2(Su[HP + k2],     wp[k2 << 10],     e0);
        e1 = dot2(Su[HP + k2 + 1], wp[(k2+1) << 10], e1);
      }
      Sf[GA + t] = pre + e0 + e1;
    }
    if (t < 128) {            // dA (uses hist slot di-1 = HV)
      float a = 0.f;
      const unsigned* wp = p.WhdA + ((size_t)di << 14) + t;
      const unsigned* hv = Su + HV + ((t >> 5) << 7);
      #pragma unroll 8
      for (int k2 = 0; k2 < 128; ++k2) a = dot2(hv[k2 & 127], wp[k2 << 7], a);
      Sf[DA + t] = a;
    } else if (t < 256) {     // dB (uses prev h)
      int c = t - 128;
      float a = 0.f;
      const unsigned* wp = p.WhdB + c;
      #pragma unroll 8
      for (int k2 = 0; k2 < 128; ++k2) a = dot2(Su[HP + k2], wp[k2 << 7], a);
      Sf[DB + c] = a;
    } else if (t < 640) {     // PH append: project slot di-1
      int q = t - 256, X = q >> 7, j = q & 127;
      float a0 = 0.f, a1 = 0.f;
      const unsigned* hv = Su + HV + (X << 7);
      const uint2* wp = (const uint2*)(p.WctPH + (X << 15)) + j;
      #pragma unroll 4
      for (int k2 = 0; k2 < 128; ++k2) {
        uint2 w = wp[k2 << 7];
        a0 = dot2(hv[k2], w.x, a0);
        a1 = dot2(hv[k2], w.y, a1);
      }
      Su[PH + (X*30 + di-1)*128 + j] = packbf2(a0, a1);
    } else if (t < 736) {     // QM append
      int q = t - 640, X = q >> 5, c = q & 31;
      float a = 0.f;
      const unsigned* wp = p.WmPQ + (X << 12) + c;
      const unsigned* hv = Su + HV + (X << 7);
      #pragma unroll 8
      for (int k2 = 0; k2 < 128; ++k2) a = dot2(hv[k2], wp[k2 << 5], a);
      Sf[QM + (X*30 + di-1)*32 + c] = a;
    } else if (t >= 768 && t < 800) {  // mem0 (prev_h part of mem-attn)
      int c = t - 768;
      float a = 0.f;
      const unsigned* wp = p.WmP0 + c;
      #pragma unroll 8
      for (int k2 = 0; k2 < 128; ++k2) a = dot2(Su[HP + k2], wp[k2 << 5], a);
      Sf[M0 + c] = a;
    }
    __syncthreads();
    // ---- R2: sw ----
    if (t < 96) {
      float a = Sf[ACA + t] + Sf[DA + t];
      Sf[ACA + t] = a;
      Sf[SW + t] = ftanh(a + Sf[DB + t] + Sf[BH + t]);
    }
    __syncthreads();
    // ---- R3: swm ----
    if (t < 32) {
      bool valid = (t < 10) || (t >= 16 && t < 26);
      if (valid) {
        float aN = 0.f, aK = 0.f, aV = 0.f;
        const float* sw0 = Sf + SW;
        const float* q0 = Sf + QM + t;
        for (int l = 0; l < di; ++l) {
          aN = fmaf(sw0[l],      q0[l*32],        aN);
          aK = fmaf(sw0[32 + l], q0[960 + l*32],  aK);
          aV = fmaf(sw0[64 + l], q0[1920 + l*32], aV);
        }
        Sf[SWM + t] = ftanh(Sf[M0 + t] + Sf[BM + t] + aN + aK + aV);
      }
    }
    __syncthreads();
    // ---- R4: c0 + LSTM cell (pairs) ----
    if (t < 128) {
      float a0 = Sf[BCT + 2*t], a1 = Sf[BCT + 2*t + 1];
      for (int X = 0; X < 3; ++X) {
        const float* swp = Sf + SW + X*32;
        const unsigned* php = Su + PH + X*3840 + t;
        float e0 = 0.f, e1 = 0.f, o0 = 0.f, o1 = 0.f;
        int l = 0;
        for (; l + 1 < di; l += 2) {
          float s0 = swp[l], s1 = swp[l+1];
          unsigned ua = php[l*128], ub = php[(l+1)*128];
          e0 = fmaf(s0, u2lo(ua), e0); e1 = fmaf(s0, u2hi(ua), e1);
          o0 = fmaf(s1, u2lo(ub), o0); o1 = fmaf(s1, u2hi(ub), o1);
        }
        if (l < di) {
          float s = swp[l]; unsigned u = php[l*128];
          e0 = fmaf(s, u2lo(u), e0); e1 = fmaf(s, u2hi(u), e1);
        }
        a0 += e0 + o0; a1 += e1 + o1;
      }
      {
        float p0 = 0.f, p1 = 0.f, q0 = 0.f, q1 = 0.f;
        #pragma unroll
        for (int m = 0; m < 10; ++m) {
          float sk = Sf[SWM + m], sv = Sf[SWM + 16 + m];
          unsigned uk = Su[P45 + m*128 + t], uv = Su[P45 + 1280 + m*128 + t];
          p0 = fmaf(sk, u2lo(uk), p0); p1 = fmaf(sk, u2hi(uk), p1);
          q0 = fmaf(sv, u2lo(uv), q0); q1 = fmaf(sv, u2hi(uv), q1);
        }
        a0 += p0 + q0; a1 += p1 + q1;
      }
      int n0 = 2*t;
      float gi0 = Sf[GA+n0],   gf0 = Sf[GA+256+n0], gg0 = Sf[GA+512+n0], go0 = Sf[GA+768+n0];
      float gi1 = Sf[GA+n0+1], gf1 = Sf[GA+257+n0], gg1 = Sf[GA+513+n0], go1 = Sf[GA+769+n0];
      float cc0 = sigf(gf0)*a0 + sigf(gi0)*ftanh(gg0);
      float cc1 = sigf(gf1)*a1 + sigf(gi1)*ftanh(gg1);
      float h0 = sigf(go0)*ftanh(cc0);
      float h1 = sigf(go1)*ftanh(cc1);
      Su[HP + t] = packbf2(h0, h1);
    }
    __syncthreads();
    // ---- R5: hN/hK/hV + gt ----
    if (t < 384) {
      int X = t >> 7, j = t & 127;
      float a0 = 0.f, a1 = 0.f;
      const uint2* wp = (const uint2*)p.WnkvP + t;
      #pragma unroll 4
      for (int k2 = 0; k2 < 128; ++k2) {
        uint2 w = wp[k2*384];
        unsigned u = Su[HP + k2];
        a0 = dot2(u, w.x, a0);
        a1 = dot2(u, w.y, a1);
      }
      unsigned up = packbf2(a0, a1);
      Su[HV + t] = up;
      if (X == 0) p.hNb[(size_t)(((di-1) << 7) | b)*128 + j] = up;
    } else if (t >= 448 && t < 512) {
      int j = t - 448;
      float a = dot2(Su[HP + 2*j], p.WgP[2*j], 0.f);
      a = dot2(Su[HP + 2*j + 1], p.WgP[2*j + 1], a);
      #pragma unroll
      for (int o = 1; o < 64; o <<= 1) a += __shfl_xor(a, o);
      if (j == 0) {
        float g = sigf(a + Sf[BG]);
        p.gt_all[((di-1) << 7) | b] = g;
        p.outg[b*L_ + di] = g;
      }
    }
    __syncthreads();
  }
}

// ---------------------------------------------------------------- vocab GEMM, B-resident: W_nv read ONCE
__global__ __launch_bounds__(256) void k_vocab(
    const bf16* hNb, const bf16* Wnvb, const float* b_nv, float2* pmps) {
  extern __shared__ char smv[];
  char* Bl = smv;             // 128 vocab rows x 256 bf16, swizzled (fixed per block)
  char* Al = smv + 65536;     // 128 hN rows x 256 bf16, swizzled (per tile)
  int ch = blockIdx.x;        // 0..249
  int t = threadIdx.x, wid = t >> 6, lane = t & 63;
  int v0 = ch * 128;
  for (int i = t; i < 128*32; i += 256) {
    int r = i >> 5, c8 = i & 31;
    int4 v = *(const int4*)(Wnvb + (size_t)(v0 + r)*H_ + c8*8);
    *(int4*)(Bl + ((r*512 + c8*16) ^ ((r&7)<<4))) = v;
  }
  float bb[8];
  #pragma unroll
  for (int fj = 0; fj < 8; ++fj) bb[fj] = b_nv[v0 + fj*16 + (lane & 15)];
  for (int tile = 0; tile < 29; ++tile) {
    __syncthreads();   // also covers initial B staging on tile 0
    for (int i = t; i < 128*32; i += 256) {
      int r = i >> 5, c8 = i & 31;
      int4 v = *(const int4*)(hNb + ((size_t)tile*128 + r)*H_ + c8*8);
      *(int4*)(Al + ((r*512 + c8*16) ^ ((r&7)<<4))) = v;
    }
    __syncthreads();
    f32x4 acc[2][8] = {};
    #pragma unroll
    for (int kk = 0; kk < 8; ++kk) {
      int kb2 = kk*64 + (lane>>4)*16;
      bf16x8 af[2], bfr[8];
      #pragma unroll
      for (int fi = 0; fi < 2; ++fi) {
        int m = wid*32 + fi*16 + (lane & 15);
        af[fi] = *(const bf16x8*)(Al + ((m*512 + kb2) ^ ((m&7)<<4)));
      }
      #pragma unroll
      for (int fj = 0; fj < 8; ++fj) {
        int n = fj*16 + (lane & 15);
        bfr[fj] = *(const bf16x8*)(Bl + ((n*512 + kb2) ^ ((n&7)<<4)));
      }
      #pragma unroll
      for (int fi = 0; fi < 2; ++fi)
        #pragma unroll
        for (int fj = 0; fj < 8; ++fj)
          acc[fi][fj] = MFMA(af[fi], bfr[fj], acc[fi][fj]);
    }
    // per-row local max & sumexp over this block's 128 cols (no streaming needed)
    #pragma unroll
    for (int fi = 0; fi < 2; ++fi)
      #pragma unroll
      for (int r = 0; r < 4; ++r) {
        float mi = acc[fi][0][r] + bb[0];
        #pragma unroll
        for (int fj = 1; fj < 8; ++fj) mi = fmaxf(mi, acc[fi][fj][r] + bb[fj]);
        for (int o = 1; o < 16; o <<= 1) mi = fmaxf(mi, __shfl_xor(mi, o));
        float si = 0.f;
        #pragma unroll
        for (int fj = 0; fj < 8; ++fj) si += __expf(acc[fi][fj][r] + bb[fj] - mi);
        for (int o = 1; o < 16; o <<= 1) si += __shfl_xor(si, o);
        if ((lane & 15) == 0) {
          int row = wid*32 + fi*16 + (lane>>4)*4 + r;
          pmps[(size_t)ch*NG + tile*128 + row] = make_float2(mi, si);
        }
      }
  }
}

// ---------------------------------------------------------------- per-step loss combine
__global__ __launch_bounds__(128) void k_combine(
    const float2* pmps, const unsigned* hNb, const float* W_nv, const float* b_nv,
    const float* gt_all, const int* sentence, float* loss_part) {
  __shared__ float red[128];
  int tile = blockIdx.x, bb = threadIdx.x;
  int g = tile*128 + bb;
  float M = -1e30f, Ssum = 0.f;
  for (int c = 0; c < NCHK; ++c) {
    float2 v = pmps[(size_t)c*NG + g];
    float M2 = fmaxf(M, v.x);
    Ssum = Ssum*__expf(M - M2) + v.y*__expf(v.x - M2);
    M = M2;
  }
  int tok = sentence[bb*L_ + tile + 1];
  float z = b_nv[tok];
  const unsigned* hu = hNb + (size_t)g*128;
  const float* wr = W_nv + (size_t)tok*H_;
  #pragma unroll 8
  for (int k = 0; k < 128; ++k) {
    unsigned w2 = hu[k];
    z += u2lo(w2)*wr[2*k] + u2hi(w2)*wr[2*k + 1];
  }
  float term = -(z - M - __logf(Ssum) + __logf(gt_all[g]));
  red[bb] = term;
  __syncthreads();
  for (int o = 64; o > 0; o >>= 1) {
    if (bb < o) red[bb] += red[bb + o];
    __syncthreads();
  }
  if (bb == 0) loss_part[tile] = red[0];
}

__global__ __launch_bounds__(64) void k_fin(const float* lp, float* out) {
  int t = threadIdx.x;
  float v = (t < 29) ? lp[t] : 0.f;
  for (int o = 1; o < 64; o <<= 1) v += __shfl_xor(v, o);
  if (t == 0) out[0] = v;
}

// ---------------------------------------------------------------- launch
extern "C" void kernel_launch(void* const* d_in, const int* in_sizes, int n_in,
                              void* d_out, int out_size, void* d_ws, size_t ws_size,
                              hipStream_t stream) {
  const int* sentence  = (const int*)d_in[0];
  const int* keywords  = (const int*)d_in[1];
  const int* categories= (const int*)d_in[2];
  const int* memsz     = (const int*)d_in[3];
  const float* emb  = (const float*)d_in[5];
  const float* W_ct = (const float*)d_in[6];
  const float* b_ct = (const float*)d_in[7];
  const float* W_ih = (const float*)d_in[8];
  const float* W_hh = (const float*)d_in[9];
  const float* b_ih = (const float*)d_in[10];
  const float* b_hh = (const float*)d_in[11];
  const float* W_n  = (const float*)d_in[12];
  const float* W_k  = (const float*)d_in[13];
  const float* W_v  = (const float*)d_in[14];
  const float* W_nv = (const float*)d_in[15];
  const float* b_nv = (const float*)d_in[16];
  const float* W_g  = (const float*)d_in[17];
  const float* b_g  = (const float*)d_in[18];
  const float* W_hn = (const float*)d_in[19];
  const float* b_hn = (const float*)d_in[20];
  const float* W_hk = (const float*)d_in[21];
  const float* b_hk = (const float*)d_in[22];
  const float* W_hv = (const float*)d_in[23];
  const float* b_hv = (const float*)d_in[24];
  const float* W_mk = (const float*)d_in[25];
  const float* b_mk = (const float*)d_in[26];
  const float* W_mv = (const float*)d_in[27];
  const float* b_mv = (const float*)d_in[28];
  float* out = (float*)d_out;

  char* wsp = (char*)d_ws;
  size_t off = 0;
  auto alloc = [&](size_t bytes) -> void* {
    void* pp = wsp + off;
    off = (off + bytes + 255) & ~(size_t)255;
    return pp;
  };
  unsigned* WhhP   = (unsigned*)alloc((size_t)131072*4);
  bf16* Wihb       = (bf16*)alloc((size_t)262144*2);
  unsigned* WnkvP  = (unsigned*)alloc((size_t)98304*4);
  unsigned* WctPH  = (unsigned*)alloc((size_t)98304*4);
  unsigned* WctP45 = (unsigned*)alloc((size_t)65536*4);
  unsigned* WmP0   = (unsigned*)alloc((size_t)4096*4);
  unsigned* WmPQ   = (unsigned*)alloc((size_t)12288*4);
  unsigned* WhdA   = (unsigned*)alloc((size_t)491520*4);
  unsigned* WhdB   = (unsigned*)alloc((size_t)16384*4);
  unsigned* WgP    = (unsigned*)alloc((size_t)128*4);
  bf16* Wnvb       = (bf16*)alloc((size_t)VN_*H_*2);
  float* prehg     = (float*)alloc((size_t)29*B_*1024*4);
  unsigned* hNb    = (unsigned*)alloc((size_t)29*B_*128*4);
  float* gt_all    = (float*)alloc((size_t)29*B_*4);
  float2* pmps     = (float2*)alloc((size_t)NCHK*NG*8);
  float* loss_part = (float*)alloc(29*4);

  k_prep<<<1024, 256, 0, stream>>>(W_ct, W_ih, W_hh, W_n, W_k, W_v, W_nv,
      W_hn, W_hk, W_hv, W_mk, W_mv, W_g,
      WhhP, Wihb, WnkvP, WctPH, WctP45, WmP0, WmPQ, WhdA, WhdB, WgP, Wnvb);
  k_pregates<<<29, 256, 131072, stream>>>(sentence, emb, Wihb, b_ih, b_hh, prehg);

  LoopP P;
  P.sentence = sentence; P.keywords = keywords; P.categories = categories; P.memsz = memsz;
  P.emb = emb;
  P.WhhP = WhhP; P.WnkvP = WnkvP; P.WctPH = WctPH; P.WctP45 = WctP45;
  P.WmP0 = WmP0; P.WmPQ = WmPQ; P.WhdA = WhdA; P.WhdB = WhdB; P.WgP = WgP;
  P.prehg = prehg;
  P.b_ct = b_ct; P.b_hn = b_hn; P.b_hk = b_hk; P.b_hv = b_hv;
  P.b_mk = b_mk; P.b_mv = b_mv; P.b_g = b_g;
  P.hNb = hNb; P.gt_all = gt_all; P.outg = out + 1;

  k_loop<<<B_, 1024, 87812, stream>>>(P);
  k_vocab<<<NCHK, 256, 131072, stream>>>((const bf16*)hNb, Wnvb, b_nv, pmps);
  k_combine<<<29, 128, 0, stream>>>(pmps, hNb, W_nv, b_nv, gt_all, sentence, loss_part);
  k_fin<<<1, 64, 0, stream>>>(loss_part, out);
}